// Round 6
// baseline (293.224 us; speedup 1.0000x reference)
//
#include <hip/hip_runtime.h>
#include <math.h>

#define B_  8
#define S_  4096
#define D_  768     // DIM == D_INNER == 768
#define K_  16      // KK
#define C_  48      // CD
#define N_  16      // NS
#define M_  (B_*S_) // 32768 rows

typedef float  f32x4  __attribute__((ext_vector_type(4)));
typedef __bf16 bf16x8 __attribute__((ext_vector_type(8)));

__device__ __forceinline__ ushort f2bf(float f) {
  uint u = __builtin_bit_cast(uint, f);
  u += 0x7FFFu + ((u >> 16) & 1u);      // round-to-nearest-even
  return (ushort)(u >> 16);
}
__device__ __forceinline__ float bf2f(ushort h) {
  return __builtin_bit_cast(float, (uint)h << 16);
}

// ---------------- weights f32 -> bf16 (w1 = in_proj rows [0,768), w2 = out_proj)
__global__ __launch_bounds__(256)
void cvt_w(const float* __restrict__ w1, const float* __restrict__ w2,
           ushort* __restrict__ o1, ushort* __restrict__ o2) {
  const int i = blockIdx.x * 256 + threadIdx.x;      // 1152*256 = 294912 = 2*147456
  const float* src; ushort* dst; int idx;
  if (i < 147456) { src = w1; dst = o1; idx = i; }
  else            { src = w2; dst = o2; idx = i - 147456; }
  float4 v = *reinterpret_cast<const float4*>(src + (size_t)idx * 4);
  ushort4 o;
  o.x = f2bf(v.x); o.y = f2bf(v.y); o.z = f2bf(v.z); o.w = f2bf(v.w);
  *reinterpret_cast<ushort4*>(dst + (size_t)idx * 4) = o;
}

// ---------------- GEMM1 + fused middle epilogue
// u0 = x @ W1^T + in_b  (MFMA, x f32 reg-staged -> bf16 LDS)
// epilogue: s = A.(Bt*Ct) via MFMA; u = silu(conv3_l(u0)+cb); d = softplus(delta+db);
// yT[l][c] = d*d*u*s.  Tile-edge conv rows (l%128 in {0,127}) use zero halo -> fixup.
__global__ __launch_bounds__(256)
void gemm1_fused(const float* __restrict__ X, const ushort* __restrict__ Wb,
                 const float* __restrict__ in_b, const float* __restrict__ delta,
                 const float* __restrict__ Bt, const float* __restrict__ Ct,
                 const float* __restrict__ Alog, const float* __restrict__ convw,
                 const float* __restrict__ convb, const float* __restrict__ dbias,
                 ushort* __restrict__ u0g, ushort* __restrict__ yT)
{
  __shared__ __align__(16) char smem[38976];
  ushort* As  = (ushort*)smem;               // [128][32] bf16 (main loop)
  ushort* Bs  = (ushort*)(smem + 8192);      // [128][32] bf16 (main loop)
  ushort* Gt  = (ushort*)smem;               // [4][128][24] bf16 (epilogue, overlaps staging)
  ushort* Ggd = (ushort*)(smem + 24576);     // 32-ushort guard (zeroed: lg=3 over-read lands here)
  ushort* Akf = (ushort*)(smem + 24640);     // [128][40] bf16, zeros at n=16..31
  float * wk0 = (float *)(smem + 34880);
  float * wk1 = (float *)(smem + 35392);
  float * wk2 = (float *)(smem + 35904);
  float * cbs = (float *)(smem + 36416);
  float * dbs = (float *)(smem + 36928);
  float * bis = (float *)(smem + 37440);
  float * ub0 = (float *)(smem + 37952);     // u0 row 63 (biased)
  float * ub1 = (float *)(smem + 38464);     // u0 row 64 (biased)

  const int lin = blockIdx.x;
  const int swz = (lin & 7) * 192 + (lin >> 3);   // XCD-contiguous chunks (1536%8==0)
  const int bn  = (swz % 6) * 128;
  const int bm  = (swz / 6) * 128;

  const int tid  = threadIdx.x;
  const int wid  = tid >> 6, lane = tid & 63;
  const int wr   = wid >> 1, wc   = wid & 1;
  const int lr   = lane & 15, lg  = lane >> 4;
  const int srow = lane >> 2;
  const int scol = (lane & 3) * 8;
  const int ar   = tid >> 1;                 // A-staging row
  const int ah   = (tid & 1) * 16;           // A-staging k-half

  // pre-stage epilogue params living OUTSIDE the staging+Gt region (>=24640)
  for (int idx = tid; idx < 128 * 16; idx += 256) {
    const int cl = idx >> 4, n = idx & 15;
    Akf[cl * 40 + n]      = f2bf(Alog[(size_t)(bn + cl) * 16 + n]);
    Akf[cl * 40 + 16 + n] = 0;               // zero pad: kills K=16..31 of the s-MFMA
  }
  if (tid < 128) {
    const int cg = bn + tid;
    wk0[tid] = convw[cg * 9 + 1];            // kh=0 (l-1); only kw=1 in-bounds
    wk1[tid] = convw[cg * 9 + 4];            // kh=1 (l)
    wk2[tid] = convw[cg * 9 + 7];            // kh=2 (l+1)
    cbs[tid] = convb[cg];
    dbs[tid] = dbias[cg];
    bis[tid] = in_b[cg];
  }

  f32x4 acc[4][4];
#pragma unroll
  for (int i = 0; i < 4; ++i)
#pragma unroll
    for (int j = 0; j < 4; ++j) acc[i][j] = (f32x4){0.f, 0.f, 0.f, 0.f};

  const float* xrow = X + (size_t)(bm + ar) * 768 + ah;
  for (int k0 = 0; k0 < 768; k0 += 32) {
    // A: reg-staged f32 -> bf16 (16 elems/thread)
    const float* xp = xrow + k0;
    f32x4 v0 = *reinterpret_cast<const f32x4*>(xp + 0);
    f32x4 v1 = *reinterpret_cast<const f32x4*>(xp + 4);
    f32x4 v2 = *reinterpret_cast<const f32x4*>(xp + 8);
    f32x4 v3 = *reinterpret_cast<const f32x4*>(xp + 12);
    bf16x8 p0 = {(__bf16)v0[0], (__bf16)v0[1], (__bf16)v0[2], (__bf16)v0[3],
                 (__bf16)v1[0], (__bf16)v1[1], (__bf16)v1[2], (__bf16)v1[3]};
    bf16x8 p1 = {(__bf16)v2[0], (__bf16)v2[1], (__bf16)v2[2], (__bf16)v2[3],
                 (__bf16)v3[0], (__bf16)v3[1], (__bf16)v3[2], (__bf16)v3[3]};
    *reinterpret_cast<bf16x8*>(&As[ar * 32 + ah])     = p0;
    *reinterpret_cast<bf16x8*>(&As[ar * 32 + ah + 8]) = p1;
    // B: global_load_lds (weights bf16)
#pragma unroll
    for (int jj = 0; jj < 2; ++jj) {
      const int j = wid * 2 + jj;
      const ushort* gb = Wb + (size_t)(bn + j * 16 + srow) * 768 + k0 + scol;
      __builtin_amdgcn_global_load_lds(
          (const __attribute__((address_space(1))) void*)gb,
          (__attribute__((address_space(3))) void*)(Bs + j * 512), 16, 0, 0);
    }
    __syncthreads();

    bf16x8 af[4], bfr[4];
    const int ab = (wr * 64 + lr) * 32 + lg * 8;
    const int bb = (wc * 64 + lr) * 32 + lg * 8;
#pragma unroll
    for (int mf = 0; mf < 4; ++mf) af[mf]  = *reinterpret_cast<const bf16x8*>(&As[ab + mf * 512]);
#pragma unroll
    for (int nf = 0; nf < 4; ++nf) bfr[nf] = *reinterpret_cast<const bf16x8*>(&Bs[bb + nf * 512]);
#pragma unroll
    for (int mf = 0; mf < 4; ++mf)
#pragma unroll
      for (int nf = 0; nf < 4; ++nf)
        acc[mf][nf] = __builtin_amdgcn_mfma_f32_16x16x32_bf16(af[mf], bfr[nf], acc[mf][nf], 0, 0, 0);
    __syncthreads();
  }

  // ================= fused epilogue =================
  const int b    = bm >> 12;        // batch
  const int l0   = bm & 4095;       // seq offset
  const int k_lo = bn / 48;

  // stage Gt[kk][l][n] = bf16(Bt*Ct); EVERY element of the stride-24 rows is
  // written (zeros for n>=16 or k>=16) so the MFMA's lg=2/3 over-reads see finite values.
#pragma unroll
  for (int kk = 0; kk < 4; ++kk) {
    const int k = k_lo + kk;
    const bool kv = (k < 16);
    for (int idx = tid; idx < 24 * 128; idx += 256) {
      const int n = idx >> 7, l = idx & 127;
      ushort v = 0;
      if (kv && n < 16) {
        const size_t gi = (((size_t)b * 16 + k) * 16 + n) * 4096 + l0 + l;
        v = f2bf(Bt[gi] * Ct[gi]);
      }
      Gt[(kk * 128 + l) * 24 + n] = v;
    }
  }
  if (tid < 32) Ggd[tid] = 0;       // guard after Gt (last-row lg=3 over-read)

  // bias add (u0 = acc + in_b), boundary u0 spill, wave-boundary row exchange
#pragma unroll
  for (int nf = 0; nf < 4; ++nf) {
    const float bv = bis[wc * 64 + nf * 16 + lr];
#pragma unroll
    for (int mf = 0; mf < 4; ++mf)
#pragma unroll
      for (int r = 0; r < 4; ++r) acc[mf][nf][r] += bv;
  }
  const size_t urow = (size_t)b * 4096 + l0;
  if (wr == 0) {
    if (lg == 0) {
#pragma unroll
      for (int nf = 0; nf < 4; ++nf) {
        const int cg = bn + wc * 64 + nf * 16 + lr;
        u0g[(urow + 0) * 768 + cg] = f2bf(acc[0][nf][0]);
        u0g[(urow + 1) * 768 + cg] = f2bf(acc[0][nf][1]);
      }
    }
    if (lg == 3) {
#pragma unroll
      for (int nf = 0; nf < 4; ++nf) ub0[wc * 64 + nf * 16 + lr] = acc[3][nf][3];  // row 63
    }
  } else {
    if (lg == 3) {
#pragma unroll
      for (int nf = 0; nf < 4; ++nf) {
        const int cg = bn + wc * 64 + nf * 16 + lr;
        u0g[(urow + 126) * 768 + cg] = f2bf(acc[3][nf][2]);
        u0g[(urow + 127) * 768 + cg] = f2bf(acc[3][nf][3]);
      }
    }
    if (lg == 0) {
#pragma unroll
      for (int nf = 0; nf < 4; ++nf) ub1[wc * 64 + nf * 16 + lr] = acc[0][nf][0];  // row 64
    }
  }
  __syncthreads();

  // compute y = d*d*u*s and store transposed
  const int l0m = l0 + wr * 64;
#pragma unroll
  for (int nf = 0; nf < 4; ++nf) {
    const int cl = wc * 64 + nf * 16 + lr;
    const int cg = bn + cl;
    const int kk = (bn + wc * 64 + nf * 16) / 48 - k_lo;   // fragment-uniform (48 = 3*16)
    const bf16x8 bA = *reinterpret_cast<const bf16x8*>(&Akf[cl * 40 + lg * 8]);
    const float w0 = wk0[cl], w1 = wk1[cl], w2 = wk2[cl];
    const float cb = cbs[cl], db = dbs[cl];
#pragma unroll
    for (int mf = 0; mf < 4; ++mf) {
      // s via MFMA: D[row=lg*4+r][col=lr] = sum_n Gt[l=mf*16+row][n]*Akf[c=col][n]
      const bf16x8 aG = *reinterpret_cast<const bf16x8*>(
          &Gt[(kk * 128 + wr * 64 + mf * 16 + lr) * 24 + lg * 8]);
      f32x4 s4 = __builtin_amdgcn_mfma_f32_16x16x32_bf16(aG, bA, (f32x4){0.f,0.f,0.f,0.f}, 0, 0, 0);

      // conv neighbors (in-register / shfl / LDS boundary)
      const float sh_in = __shfl(acc[mf][nf][3], lane - 16, 64);
      float sh_pf = 0.f;
      if (mf > 0) sh_pf = __shfl(acc[mf - 1][nf][3], lane + 48, 64);
      const float below0 = (lg > 0) ? sh_in
                         : ((mf > 0) ? sh_pf : (wr ? ub0[cl] : 0.f));
      const float sh_ia = __shfl(acc[mf][nf][0], lane + 16, 64);
      float sh_na = 0.f;
      if (mf < 3) sh_na = __shfl(acc[mf + 1][nf][0], lane - 48, 64);
      const float above3 = (lg < 3) ? sh_ia
                         : ((mf < 3) ? sh_na : ((wr == 0) ? ub1[cl] : 0.f));

      const f32x4 dly = *reinterpret_cast<const f32x4*>(
          &delta[((size_t)b * 768 + cg) * 4096 + l0m + mf * 16 + lg * 4]);

#pragma unroll
      for (int r = 0; r < 4; ++r) {
        const float um1 = (r == 0) ? below0 : acc[mf][nf][r - 1];
        const float up1 = (r == 3) ? above3 : acc[mf][nf][r + 1];
        const float xx  = fmaf(w0, um1, fmaf(w1, acc[mf][nf][r], fmaf(w2, up1, cb)));
        const float u   = xx * __builtin_amdgcn_rcpf(1.f + __expf(-xx));
        const float dv  = dly[r] + db;
        const float d   = (dv > 15.f) ? dv : __logf(1.f + __expf(dv));
        yT[((size_t)b * 4096 + l0m + mf * 16 + lg * 4 + r) * 768 + cg] = f2bf(d * d * u * s4[r]);
      }
    }
  }
}

// ---------------- fixup: recompute y rows adjacent to tile boundaries (l = 128j+127, 128j+128)
__global__ __launch_bounds__(256)
void fixup(const ushort* __restrict__ u0g, const float* __restrict__ delta,
           const float* __restrict__ Bt, const float* __restrict__ Ct,
           const float* __restrict__ Alog, const float* __restrict__ convw,
           const float* __restrict__ convb, const float* __restrict__ dbias,
           ushort* __restrict__ yT)
{
  __shared__ ushort U[4 * 768];     // u0 rows lb-2 .. lb+1
  __shared__ float  G2[2][256];     // Bt*Ct at ly = lb-1, lb
  const int j  = blockIdx.x, b = blockIdx.y;
  const int lb = 128 * (j + 1);
  const int tid = threadIdx.x;

  const uint* us = reinterpret_cast<const uint*>(u0g + ((size_t)b * 4096 + lb - 2) * 768);
  uint* ud = reinterpret_cast<uint*>(U);
  for (int i = tid; i < 4 * 384; i += 256) ud[i] = us[i];
  for (int i = tid; i < 512; i += 256) {
    const int r = i >> 8, kn = i & 255;
    const size_t gi = ((size_t)b * 256 + kn) * 4096 + lb - 1 + r;
    G2[r][kn] = Bt[gi] * Ct[gi];
  }
  __syncthreads();

  for (int e = tid; e < 1536; e += 256) {
    const int r = (e < 768) ? 0 : 1;
    const int c = e - r * 768;
    const int ly = lb - 1 + r;
    const int k = c / 48;
    float dv = delta[((size_t)b * 768 + c) * 4096 + ly] + dbias[c];
    const float d = (dv > 15.f) ? dv : __logf(1.f + __expf(dv));
    const float xx = fmaf(convw[c * 9 + 1], bf2f(U[r * 768 + c]),
                     fmaf(convw[c * 9 + 4], bf2f(U[(r + 1) * 768 + c]),
                     fmaf(convw[c * 9 + 7], bf2f(U[(r + 2) * 768 + c]), convb[c])));
    const float u = xx * __builtin_amdgcn_rcpf(1.f + __expf(-xx));
    float s = 0.f;
#pragma unroll
    for (int n = 0; n < 16; ++n) s = fmaf(Alog[c * 16 + n], G2[r][k * 16 + n], s);
    yT[((size_t)b * 4096 + ly) * 768 + c] = f2bf(d * d * u * s);
  }
}

// ---------------- GEMM2 (m97 structure): out = yT @ W2^T + out_b  (f32 out)
__global__ __launch_bounds__(256)
void gemm_mfma_bt(const ushort* __restrict__ A, const ushort* __restrict__ Bm,
                  const float* __restrict__ bias, float* __restrict__ Cc)
{
  __shared__ ushort As[128 * 32];
  __shared__ ushort Bs[128 * 32];

  const int lin = blockIdx.x;
  const int swz = (lin & 7) * 192 + (lin >> 3);
  const int bn  = (swz % 6) * 128;
  const int bm  = (swz / 6) * 128;

  const int tid  = threadIdx.x;
  const int wid  = tid >> 6, lane = tid & 63;
  const int wr   = wid >> 1, wc   = wid & 1;
  const int lr   = lane & 15, lg  = lane >> 4;
  const int srow = lane >> 2;
  const int scol = (lane & 3) * 8;

  f32x4 acc[4][4];
#pragma unroll
  for (int i = 0; i < 4; ++i)
#pragma unroll
    for (int j = 0; j < 4; ++j) acc[i][j] = (f32x4){0.f, 0.f, 0.f, 0.f};

  for (int k0 = 0; k0 < 768; k0 += 32) {
#pragma unroll
    for (int jj = 0; jj < 2; ++jj) {
      const int j = wid * 2 + jj;
      const ushort* ga = A  + (size_t)(bm + j * 16 + srow) * 768 + k0 + scol;
      __builtin_amdgcn_global_load_lds(
          (const __attribute__((address_space(1))) void*)ga,
          (__attribute__((address_space(3))) void*)(As + j * 512), 16, 0, 0);
      const ushort* gb = Bm + (size_t)(bn + j * 16 + srow) * 768 + k0 + scol;
      __builtin_amdgcn_global_load_lds(
          (const __attribute__((address_space(1))) void*)gb,
          (__attribute__((address_space(3))) void*)(Bs + j * 512), 16, 0, 0);
    }
    __syncthreads();

    bf16x8 af[4], bfr[4];
    const int ab = (wr * 64 + lr) * 32 + lg * 8;
    const int bb = (wc * 64 + lr) * 32 + lg * 8;
#pragma unroll
    for (int mf = 0; mf < 4; ++mf) af[mf]  = *reinterpret_cast<const bf16x8*>(&As[ab + mf * 512]);
#pragma unroll
    for (int nf = 0; nf < 4; ++nf) bfr[nf] = *reinterpret_cast<const bf16x8*>(&Bs[bb + nf * 512]);
#pragma unroll
    for (int mf = 0; mf < 4; ++mf)
#pragma unroll
      for (int nf = 0; nf < 4; ++nf)
        acc[mf][nf] = __builtin_amdgcn_mfma_f32_16x16x32_bf16(af[mf], bfr[nf], acc[mf][nf], 0, 0, 0);
    __syncthreads();
  }

#pragma unroll
  for (int nf = 0; nf < 4; ++nf) {
    const int n  = bn + wc * 64 + nf * 16 + lr;
    const float bv = bias[n];
#pragma unroll
    for (int mf = 0; mf < 4; ++mf) {
      const int m0 = bm + wr * 64 + mf * 16 + lg * 4;
#pragma unroll
      for (int r = 0; r < 4; ++r)
        Cc[(size_t)(m0 + r) * 768 + n] = acc[mf][nf][r] + bv;
    }
  }
}

extern "C" void kernel_launch(void* const* d_in, const int* in_sizes, int n_in,
                              void* d_out, int out_size, void* d_ws, size_t ws_size,
                              hipStream_t stream) {
  const float* x      = (const float*)d_in[0];
  const float* in_w   = (const float*)d_in[1];   // (1536,768) — only rows [0,768) used
  const float* in_b   = (const float*)d_in[2];
  const float* convw  = (const float*)d_in[3];
  const float* convb  = (const float*)d_in[4];
  const float* out_w  = (const float*)d_in[5];
  const float* out_b  = (const float*)d_in[6];
  const float* Alog   = (const float*)d_in[7];
  const float* delta  = (const float*)d_in[8];
  const float* Bt     = (const float*)d_in[9];
  const float* Ct     = (const float*)d_in[10];
  const float* dbias  = (const float*)d_in[11];
  float* out = (float*)d_out;

  ushort* u0g = (ushort*)d_ws;               // (B,S,768) bf16 (only tile-edge rows written)
  ushort* yTb = u0g + (size_t)M_ * D_;       // (B,S,768) bf16
  ushort* wb1 = yTb + (size_t)M_ * D_;
  ushort* wb2 = wb1 + (size_t)D_ * D_;

  cvt_w<<<1152, 256, 0, stream>>>(in_w, out_w, wb1, wb2);
  gemm1_fused<<<1536, 256, 0, stream>>>(x, wb1, in_b, delta, Bt, Ct, Alog,
                                        convw, convb, dbias, u0g, yTb);
  fixup<<<dim3(31, 8), 256, 0, stream>>>(u0g, delta, Bt, Ct, Alog, convw, convb, dbias, yTb);
  gemm_mfma_bt<<<1536, 256, 0, stream>>>(yTb, wb2, out_b, out);
}

// Round 7
// 259.594 us; speedup vs baseline: 1.1295x; 1.1295x over previous
//
#include <hip/hip_runtime.h>
#include <math.h>

#define B_  8
#define S_  4096
#define D_  768     // DIM == D_INNER == 768
#define K_  16      // KK
#define C_  48      // CD
#define N_  16      // NS
#define M_  (B_*S_) // 32768 rows

typedef float  f32x4  __attribute__((ext_vector_type(4)));
typedef __bf16 bf16x8 __attribute__((ext_vector_type(8)));

__device__ __forceinline__ ushort f2bf(float f) {
  uint u = __builtin_bit_cast(uint, f);
  u += 0x7FFFu + ((u >> 16) & 1u);      // round-to-nearest-even
  return (ushort)(u >> 16);
}
__device__ __forceinline__ float bf2f(ushort h) {
  return __builtin_bit_cast(float, (uint)h << 16);
}

// ---------------- weights f32 -> bf16 (w1 = in_proj rows [0,768), w2 = out_proj)
__global__ __launch_bounds__(256)
void cvt_w(const float* __restrict__ w1, const float* __restrict__ w2,
           ushort* __restrict__ o1, ushort* __restrict__ o2) {
  const int i = blockIdx.x * 256 + threadIdx.x;      // 1152*256 = 2*147456
  const float* src; ushort* dst; int idx;
  if (i < 147456) { src = w1; dst = o1; idx = i; }
  else            { src = w2; dst = o2; idx = i - 147456; }
  float4 v = *reinterpret_cast<const float4*>(src + (size_t)idx * 4);
  ushort4 o;
  o.x = f2bf(v.x); o.y = f2bf(v.y); o.z = f2bf(v.z); o.w = f2bf(v.w);
  *reinterpret_cast<ushort4*>(dst + (size_t)idx * 4) = o;
}

// ---------------- GEMM1: u0T = (x @ W1^T + in_b) stored TRANSPOSED [c][l] bf16
// A = f32 X reg-staged -> bf16 LDS (conflict-free byte=tid*16 mapping); B = gload_lds.
__global__ __launch_bounds__(256)
void gemm1_xf32(const float* __restrict__ X, const ushort* __restrict__ Wb,
                const float* __restrict__ in_b, ushort* __restrict__ u0T)
{
  __shared__ ushort As[128 * 32];   // 8 KB linear [row][k]
  __shared__ ushort Bs[128 * 32];

  const int lin = blockIdx.x;
  const int swz = (lin & 7) * 192 + (lin >> 3);   // XCD swizzle (1536%8==0 bijective)
  const int bn  = (swz % 6) * 128;
  const int bm  = (swz / 6) * 128;

  const int tid  = threadIdx.x;
  const int wid  = tid >> 6, lane = tid & 63;
  const int wr   = wid >> 1, wc   = wid & 1;
  const int lr   = lane & 15, lg  = lane >> 4;
  const int srow = lane >> 2;
  const int scol = (lane & 3) * 8;
  const int arow = tid >> 2;                 // A-staging: rows arow, arow+64
  const int acol = (tid & 3) * 8;            // 8 bf16 per 16B write, byte = tid*16

  f32x4 acc[4][4];
#pragma unroll
  for (int i = 0; i < 4; ++i)
#pragma unroll
    for (int j = 0; j < 4; ++j) acc[i][j] = (f32x4){0.f, 0.f, 0.f, 0.f};

  for (int k0 = 0; k0 < 768; k0 += 32) {
    // A: f32 -> bf16 reg-stage, conflict-free b128 LDS writes
#pragma unroll
    for (int half = 0; half < 2; ++half) {
      const int row = arow + half * 64;
      const float* xp = X + (size_t)(bm + row) * 768 + k0 + acol;
      f32x4 v0 = *reinterpret_cast<const f32x4*>(xp);
      f32x4 v1 = *reinterpret_cast<const f32x4*>(xp + 4);
      bf16x8 p = {(__bf16)v0[0], (__bf16)v0[1], (__bf16)v0[2], (__bf16)v0[3],
                  (__bf16)v1[0], (__bf16)v1[1], (__bf16)v1[2], (__bf16)v1[3]};
      *reinterpret_cast<bf16x8*>(&As[row * 32 + acol]) = p;
    }
    // B: global_load_lds (weights bf16)
#pragma unroll
    for (int jj = 0; jj < 2; ++jj) {
      const int j = wid * 2 + jj;
      const ushort* gb = Wb + (size_t)(bn + j * 16 + srow) * 768 + k0 + scol;
      __builtin_amdgcn_global_load_lds(
          (const __attribute__((address_space(1))) void*)gb,
          (__attribute__((address_space(3))) void*)(Bs + j * 512), 16, 0, 0);
    }
    __syncthreads();

    bf16x8 af[4], bfr[4];
    const int ab = (wr * 64 + lr) * 32 + lg * 8;
    const int bb = (wc * 64 + lr) * 32 + lg * 8;
#pragma unroll
    for (int mf = 0; mf < 4; ++mf) af[mf]  = *reinterpret_cast<const bf16x8*>(&As[ab + mf * 512]);
#pragma unroll
    for (int nf = 0; nf < 4; ++nf) bfr[nf] = *reinterpret_cast<const bf16x8*>(&Bs[bb + nf * 512]);
#pragma unroll
    for (int mf = 0; mf < 4; ++mf)
#pragma unroll
      for (int nf = 0; nf < 4; ++nf)
        acc[mf][nf] = __builtin_amdgcn_mfma_f32_16x16x32_bf16(af[mf], bfr[nf], acc[mf][nf], 0, 0, 0);
    __syncthreads();
  }

  // epilogue: transposed store u0T[(b*768 + c)*4096 + l], 8B per lane (4 consecutive l)
  const int b   = bm >> 12;
  const int l0g = (bm & 4095) + wr * 64;
#pragma unroll
  for (int nf = 0; nf < 4; ++nf) {
    const int cg = bn + wc * 64 + nf * 16 + lr;
    const float bv = in_b[cg];
    ushort* up = u0T + ((size_t)b * 768 + cg) * 4096 + l0g;
#pragma unroll
    for (int mf = 0; mf < 4; ++mf) {
      ushort4 o;
      o.x = f2bf(acc[mf][nf][0] + bv);
      o.y = f2bf(acc[mf][nf][1] + bv);
      o.z = f2bf(acc[mf][nf][2] + bv);
      o.w = f2bf(acc[mf][nf][3] + bv);
      *reinterpret_cast<ushort4*>(up + mf * 16 + lg * 4) = o;
    }
  }
}

// ---------------- fused middle: conv3+silu (u0T direct from global), softplus(delta),
// einsum, d*d*u*s, bf16 [l][c] store. Wave-uniform c, dl = lane, 2-deep prefetch.
#define YSP 70

__global__ __launch_bounds__(256)
void fuse_mid(const ushort* __restrict__ u0T, const float* __restrict__ delta,
              const float* __restrict__ Bt, const float* __restrict__ Ct,
              const float* __restrict__ Alog, const float* __restrict__ convw,
              const float* __restrict__ convb, const float* __restrict__ dbias,
              ushort* __restrict__ yT)
{
  __shared__ float  Gs [N_ * 64];       // [n][dl]  B*C products (4 KB)
  __shared__ float  Ak [C_ * N_];       // [c][n]   A rows (3 KB, broadcast reads)
  __shared__ ushort Ys [C_ * YSP];      // [c][dl]  result bounce (6.6 KB)
  __shared__ float  Wk0[C_], Wk1[C_], Wk2[C_], CB[C_], DB[C_];

  const int tid = threadIdx.x;
  const int wid = tid >> 6, lane = tid & 63;
  const int lt = blockIdx.x, k = blockIdx.y, b = blockIdx.z;
  const int l0 = lt * 64;

  for (int idx = tid; idx < N_ * 64; idx += 256) {
    const int n = idx >> 6, dl = idx & 63;
    const size_t gg = (((size_t)b * K_ + k) * N_ + n) * S_ + l0 + dl;
    Gs[idx] = Bt[gg] * Ct[gg];
  }
  for (int idx = tid; idx < C_ * N_; idx += 256)
    Ak[idx] = Alog[(size_t)k * C_ * N_ + idx];
  if (tid < C_) {
    Wk0[tid] = convw[(k * C_ + tid) * 9 + 1];   // only kw=1 column in-bounds (W=1, pad 1)
    Wk1[tid] = convw[(k * C_ + tid) * 9 + 4];
    Wk2[tid] = convw[(k * C_ + tid) * 9 + 7];
    CB [tid] = convb[k * C_ + tid];
    DB [tid] = dbias[k * C_ + tid];
  }
  __syncthreads();

  float g[N_];
#pragma unroll
  for (int n = 0; n < N_; ++n) g[n] = Gs[n * 64 + lane];

  // 2-deep rotating prefetch of delta + u0 conv taps (channel stride 4 rows)
  const int  gl    = l0 + lane;
  const bool lm_ok = gl > 0;
  const bool lp_ok = gl < (S_ - 1);
  const size_t base = ((size_t)b * D_ + k * C_ + wid) * S_ + gl;
  const float*  dp = delta + base;
  const ushort* up = u0T + base;
  const size_t cs = (size_t)4 * S_;

  float dA = dp[0];
  float umA = lm_ok ? bf2f(up[-1]) : 0.f;
  float u0A = bf2f(up[0]);
  float upA = lp_ok ? bf2f(up[1]) : 0.f;
  float dB = dp[cs];
  float umB = lm_ok ? bf2f(up[cs - 1]) : 0.f;
  float u0B = bf2f(up[cs]);
  float upB = lp_ok ? bf2f(up[cs + 1]) : 0.f;

  for (int step = 0; step < 12; ++step) {
    const int c = step * 4 + wid;
    const float dcur = dA, um = umA, u0v = u0A, upv = upA;
    dA = dB; umA = umB; u0A = u0B; upA = upB;
    if (step < 10) {
      const size_t off = (size_t)(step + 2) * cs;
      dB  = dp[off];
      umB = lm_ok ? bf2f(up[off - 1]) : 0.f;
      u0B = bf2f(up[off]);
      upB = lp_ok ? bf2f(up[off + 1]) : 0.f;
    }

    float a[N_];
#pragma unroll
    for (int n4i = 0; n4i < 4; ++n4i)   // broadcast ds_read_b128 x4 (uniform address)
      *reinterpret_cast<f32x4*>(&a[n4i * 4]) =
          *reinterpret_cast<const f32x4*>(&Ak[c * N_ + n4i * 4]);

    const float dv = dcur + DB[c];
    const float d  = (dv > 15.f) ? dv : __logf(1.f + __expf(dv));   // softplus

    float xx = fmaf(Wk0[c], um, fmaf(Wk1[c], u0v, fmaf(Wk2[c], upv, CB[c])));
    const float u = xx * __builtin_amdgcn_rcpf(1.f + __expf(-xx));  // silu

    float s = 0.f;
#pragma unroll
    for (int n = 0; n < N_; ++n) s = fmaf(a[n], g[n], s);

    Ys[c * YSP + lane] = f2bf(d * d * u * s);
  }
  __syncthreads();

  // [l][c] store as packed uints (2 channels per store); incremental div (256 = 10*24+16)
  {
    uint* yTu = reinterpret_cast<uint*>(yT);
    int dl = tid / 24, j = tid - (tid / 24) * 24;
    for (int e = tid; e < 64 * 24; e += 256) {
      const uint lo = Ys[(2 * j    ) * YSP + dl];
      const uint hi = Ys[(2 * j + 1) * YSP + dl];
      yTu[((size_t)b * S_ + l0 + dl) * 384 + k * 24 + j] = lo | (hi << 16);
      dl += 10; j += 16; if (j >= 24) { j -= 24; dl += 1; }
    }
  }
}

// ---------------- GEMM2 (m97 structure): out = yT @ W2^T + out_b  (f32 out)
__global__ __launch_bounds__(256)
void gemm_mfma_bt(const ushort* __restrict__ A, const ushort* __restrict__ Bm,
                  const float* __restrict__ bias, float* __restrict__ Cc)
{
  __shared__ ushort As[128 * 32];
  __shared__ ushort Bs[128 * 32];

  const int lin = blockIdx.x;
  const int swz = (lin & 7) * 192 + (lin >> 3);
  const int bn  = (swz % 6) * 128;
  const int bm  = (swz / 6) * 128;

  const int tid  = threadIdx.x;
  const int wid  = tid >> 6, lane = tid & 63;
  const int wr   = wid >> 1, wc   = wid & 1;
  const int lr   = lane & 15, lg  = lane >> 4;
  const int srow = lane >> 2;
  const int scol = (lane & 3) * 8;

  f32x4 acc[4][4];
#pragma unroll
  for (int i = 0; i < 4; ++i)
#pragma unroll
    for (int j = 0; j < 4; ++j) acc[i][j] = (f32x4){0.f, 0.f, 0.f, 0.f};

  for (int k0 = 0; k0 < 768; k0 += 32) {
#pragma unroll
    for (int jj = 0; jj < 2; ++jj) {
      const int j = wid * 2 + jj;
      const ushort* ga = A  + (size_t)(bm + j * 16 + srow) * 768 + k0 + scol;
      __builtin_amdgcn_global_load_lds(
          (const __attribute__((address_space(1))) void*)ga,
          (__attribute__((address_space(3))) void*)(As + j * 512), 16, 0, 0);
      const ushort* gb = Bm + (size_t)(bn + j * 16 + srow) * 768 + k0 + scol;
      __builtin_amdgcn_global_load_lds(
          (const __attribute__((address_space(1))) void*)gb,
          (__attribute__((address_space(3))) void*)(Bs + j * 512), 16, 0, 0);
    }
    __syncthreads();

    bf16x8 af[4], bfr[4];
    const int ab = (wr * 64 + lr) * 32 + lg * 8;
    const int bb = (wc * 64 + lr) * 32 + lg * 8;
#pragma unroll
    for (int mf = 0; mf < 4; ++mf) af[mf]  = *reinterpret_cast<const bf16x8*>(&As[ab + mf * 512]);
#pragma unroll
    for (int nf = 0; nf < 4; ++nf) bfr[nf] = *reinterpret_cast<const bf16x8*>(&Bs[bb + nf * 512]);
#pragma unroll
    for (int mf = 0; mf < 4; ++mf)
#pragma unroll
      for (int nf = 0; nf < 4; ++nf)
        acc[mf][nf] = __builtin_amdgcn_mfma_f32_16x16x32_bf16(af[mf], bfr[nf], acc[mf][nf], 0, 0, 0);
    __syncthreads();
  }

#pragma unroll
  for (int nf = 0; nf < 4; ++nf) {
    const int n  = bn + wc * 64 + nf * 16 + lr;
    const float bv = bias[n];
#pragma unroll
    for (int mf = 0; mf < 4; ++mf) {
      const int m0 = bm + wr * 64 + mf * 16 + lg * 4;
#pragma unroll
      for (int r = 0; r < 4; ++r)
        Cc[(size_t)(m0 + r) * 768 + n] = acc[mf][nf][r] + bv;
    }
  }
}

extern "C" void kernel_launch(void* const* d_in, const int* in_sizes, int n_in,
                              void* d_out, int out_size, void* d_ws, size_t ws_size,
                              hipStream_t stream) {
  const float* x      = (const float*)d_in[0];
  const float* in_w   = (const float*)d_in[1];   // (1536,768) — only rows [0,768) used
  const float* in_b   = (const float*)d_in[2];
  const float* convw  = (const float*)d_in[3];
  const float* convb  = (const float*)d_in[4];
  const float* out_w  = (const float*)d_in[5];
  const float* out_b  = (const float*)d_in[6];
  const float* Alog   = (const float*)d_in[7];
  const float* delta  = (const float*)d_in[8];
  const float* Bt     = (const float*)d_in[9];
  const float* Ct     = (const float*)d_in[10];
  const float* dbias  = (const float*)d_in[11];
  float* out = (float*)d_out;

  ushort* u0T = (ushort*)d_ws;               // (B,768,S) bf16 — TRANSPOSED u0
  ushort* yTb = u0T + (size_t)M_ * D_;       // (B,S,768) bf16
  ushort* wb1 = yTb + (size_t)M_ * D_;
  ushort* wb2 = wb1 + (size_t)D_ * D_;

  cvt_w<<<1152, 256, 0, stream>>>(in_w, out_w, wb1, wb2);
  gemm1_xf32<<<1536, 256, 0, stream>>>(x, wb1, in_b, u0T);
  fuse_mid<<<dim3(S_ / 64, K_, B_), 256, 0, stream>>>(u0T, delta, Bt, Ct, Alog,
                                                      convw, convb, dbias, yTb);
  gemm_mfma_bt<<<1536, 256, 0, stream>>>(yTb, wb2, out_b, out);
}

// Round 9
// 237.916 us; speedup vs baseline: 1.2325x; 1.0911x over previous
//
#include <hip/hip_runtime.h>
#include <math.h>

#define B_  8
#define S_  4096
#define D_  768     // DIM == D_INNER == 768
#define K_  16      // KK
#define C_  48      // CD
#define N_  16      // NS
#define M_  (B_*S_) // 32768 rows

typedef float  f32x4  __attribute__((ext_vector_type(4)));
typedef __bf16 bf16x8 __attribute__((ext_vector_type(8)));

__device__ __forceinline__ ushort f2bf(float f) {
  uint u = __builtin_bit_cast(uint, f);
  u += 0x7FFFu + ((u >> 16) & 1u);      // round-to-nearest-even
  return (ushort)(u >> 16);
}
__device__ __forceinline__ float bf2f(ushort h) {
  return __builtin_bit_cast(float, (uint)h << 16);
}

// ---------------- weights f32 -> bf16 (w1 = in_proj rows [0,768), w2 = out_proj)
__global__ __launch_bounds__(256)
void cvt_w(const float* __restrict__ w1, const float* __restrict__ w2,
           ushort* __restrict__ o1, ushort* __restrict__ o2) {
  const int i = blockIdx.x * 256 + threadIdx.x;      // 1152*256 = 2*147456
  const float* src; ushort* dst; int idx;
  if (i < 147456) { src = w1; dst = o1; idx = i; }
  else            { src = w2; dst = o2; idx = i - 147456; }
  float4 v = *reinterpret_cast<const float4*>(src + (size_t)idx * 4);
  ushort4 o;
  o.x = f2bf(v.x); o.y = f2bf(v.y); o.z = f2bf(v.z); o.w = f2bf(v.w);
  *reinterpret_cast<ushort4*>(dst + (size_t)idx * 4) = o;
}

// ---------------- GEMM1: u0T = (x @ W1^T + in_b) stored TRANSPOSED [c][l] bf16
// A = f32 X reg-staged -> bf16 LDS (conflict-free byte=tid*16 mapping); B = gload_lds.
__global__ __launch_bounds__(256)
void gemm1_xf32(const float* __restrict__ X, const ushort* __restrict__ Wb,
                const float* __restrict__ in_b, ushort* __restrict__ u0T)
{
  __shared__ ushort As[128 * 32];   // 8 KB linear [row][k]
  __shared__ ushort Bs[128 * 32];

  const int lin = blockIdx.x;
  const int swz = (lin & 7) * 192 + (lin >> 3);   // XCD swizzle (1536%8==0 bijective)
  const int bn  = (swz % 6) * 128;
  const int bm  = (swz / 6) * 128;

  const int tid  = threadIdx.x;
  const int wid  = tid >> 6, lane = tid & 63;
  const int wr   = wid >> 1, wc   = wid & 1;
  const int lr   = lane & 15, lg  = lane >> 4;
  const int srow = lane >> 2;
  const int scol = (lane & 3) * 8;
  const int arow = tid >> 2;                 // A-staging: rows arow, arow+64
  const int acol = (tid & 3) * 8;            // 8 bf16 per 16B write, byte = tid*16

  f32x4 acc[4][4];
#pragma unroll
  for (int i = 0; i < 4; ++i)
#pragma unroll
    for (int j = 0; j < 4; ++j) acc[i][j] = (f32x4){0.f, 0.f, 0.f, 0.f};

  for (int k0 = 0; k0 < 768; k0 += 32) {
    // A: f32 -> bf16 reg-stage, conflict-free b128 LDS writes
#pragma unroll
    for (int half = 0; half < 2; ++half) {
      const int row = arow + half * 64;
      const float* xp = X + (size_t)(bm + row) * 768 + k0 + acol;
      f32x4 v0 = *reinterpret_cast<const f32x4*>(xp);
      f32x4 v1 = *reinterpret_cast<const f32x4*>(xp + 4);
      bf16x8 p = {(__bf16)v0[0], (__bf16)v0[1], (__bf16)v0[2], (__bf16)v0[3],
                  (__bf16)v1[0], (__bf16)v1[1], (__bf16)v1[2], (__bf16)v1[3]};
      *reinterpret_cast<bf16x8*>(&As[row * 32 + acol]) = p;
    }
    // B: global_load_lds (weights bf16)
#pragma unroll
    for (int jj = 0; jj < 2; ++jj) {
      const int j = wid * 2 + jj;
      const ushort* gb = Wb + (size_t)(bn + j * 16 + srow) * 768 + k0 + scol;
      __builtin_amdgcn_global_load_lds(
          (const __attribute__((address_space(1))) void*)gb,
          (__attribute__((address_space(3))) void*)(Bs + j * 512), 16, 0, 0);
    }
    __syncthreads();

    bf16x8 af[4], bfr[4];
    const int ab = (wr * 64 + lr) * 32 + lg * 8;
    const int bb = (wc * 64 + lr) * 32 + lg * 8;
#pragma unroll
    for (int mf = 0; mf < 4; ++mf) af[mf]  = *reinterpret_cast<const bf16x8*>(&As[ab + mf * 512]);
#pragma unroll
    for (int nf = 0; nf < 4; ++nf) bfr[nf] = *reinterpret_cast<const bf16x8*>(&Bs[bb + nf * 512]);
#pragma unroll
    for (int mf = 0; mf < 4; ++mf)
#pragma unroll
      for (int nf = 0; nf < 4; ++nf)
        acc[mf][nf] = __builtin_amdgcn_mfma_f32_16x16x32_bf16(af[mf], bfr[nf], acc[mf][nf], 0, 0, 0);
    __syncthreads();
  }

  // epilogue: transposed store u0T[(b*768 + c)*4096 + l], 8B per lane (4 consecutive l)
  const int b   = bm >> 12;
  const int l0g = (bm & 4095) + wr * 64;
#pragma unroll
  for (int nf = 0; nf < 4; ++nf) {
    const int cg = bn + wc * 64 + nf * 16 + lr;
    const float bv = in_b[cg];
    ushort* up = u0T + ((size_t)b * 768 + cg) * 4096 + l0g;
#pragma unroll
    for (int mf = 0; mf < 4; ++mf) {
      ushort4 o;
      o.x = f2bf(acc[mf][nf][0] + bv);
      o.y = f2bf(acc[mf][nf][1] + bv);
      o.z = f2bf(acc[mf][nf][2] + bv);
      o.w = f2bf(acc[mf][nf][3] + bv);
      *reinterpret_cast<ushort4*>(up + mf * 16 + lg * 4) = o;
    }
  }
}

// ---------------- fused middle: conv3+silu (u0T single-load + UNCONDITIONAL shfl
// neighbors, then select halo), softplus(delta), einsum, d*d*u*s, bf16 [l][c] store.
#define YSP 70

__global__ __launch_bounds__(256)
void fuse_mid(const ushort* __restrict__ u0T, const float* __restrict__ delta,
              const float* __restrict__ Bt, const float* __restrict__ Ct,
              const float* __restrict__ Alog, const float* __restrict__ convw,
              const float* __restrict__ convb, const float* __restrict__ dbias,
              ushort* __restrict__ yT)
{
  __shared__ float  Gs [N_ * 64];       // [n][dl]  B*C products (4 KB)
  __shared__ float  Ak [C_ * N_];       // [c][n]   A rows (3 KB, broadcast reads)
  __shared__ ushort Ys [C_ * YSP];      // [c][dl]  result bounce (6.6 KB)
  __shared__ float  Wk0[C_], Wk1[C_], Wk2[C_], CB[C_], DB[C_];

  const int tid = threadIdx.x;
  const int wid = tid >> 6, lane = tid & 63;
  const int lt = blockIdx.x, k = blockIdx.y, b = blockIdx.z;
  const int l0 = lt * 64;

  for (int idx = tid; idx < N_ * 64; idx += 256) {
    const int n = idx >> 6, dl = idx & 63;
    const size_t gg = (((size_t)b * K_ + k) * N_ + n) * S_ + l0 + dl;
    Gs[idx] = Bt[gg] * Ct[gg];
  }
  for (int idx = tid; idx < C_ * N_; idx += 256)
    Ak[idx] = Alog[(size_t)k * C_ * N_ + idx];
  if (tid < C_) {
    Wk0[tid] = convw[(k * C_ + tid) * 9 + 1];   // only kw=1 column in-bounds (W=1, pad 1)
    Wk1[tid] = convw[(k * C_ + tid) * 9 + 4];
    Wk2[tid] = convw[(k * C_ + tid) * 9 + 7];
    CB [tid] = convb[k * C_ + tid];
    DB [tid] = dbias[k * C_ + tid];
  }
  __syncthreads();

  float g[N_];
#pragma unroll
  for (int n = 0; n < N_; ++n) g[n] = Gs[n * 64 + lane];

  // per-step loads: delta f32 + u0T bf16 (1 each, coalesced) + 2-lane halo; 2-deep prefetch
  const int  gl = l0 + lane;
  const size_t base = ((size_t)b * D_ + k * C_ + wid) * S_ + gl;
  const float*  dp = delta + base;
  const ushort* up = u0T + base;
  const size_t cs = (size_t)4 * S_;

  const bool edge_lo = (lane == 0);
  const bool edge_hi = (lane == 63);
  const int  hoff    = edge_lo ? -1 : 1;
  const bool h_ok    = (edge_lo && gl > 0) || (edge_hi && gl + 1 < S_);

  float dA = dp[0];
  float uA = bf2f(up[0]);
  float hA = h_ok ? bf2f(up[hoff]) : 0.f;
  float dB = dp[cs];
  float uB = bf2f(up[cs]);
  float hB = h_ok ? bf2f(up[cs + hoff]) : 0.f;

  for (int step = 0; step < 12; ++step) {
    const int c = step * 4 + wid;
    const float dcur = dA, u0v = uA, hv = hA;
    dA = dB; uA = uB; hA = hB;
    if (step < 10) {
      const size_t off = (size_t)(step + 2) * cs;
      dB = dp[off];
      uB = bf2f(up[off]);
      hB = h_ok ? bf2f(up[off + hoff]) : 0.f;
    }

    float a[N_];
#pragma unroll
    for (int n4i = 0; n4i < 4; ++n4i)   // broadcast ds_read_b128 x4 (uniform address)
      *reinterpret_cast<f32x4*>(&a[n4i * 4]) =
          *reinterpret_cast<const f32x4*>(&Ak[c * N_ + n4i * 4]);

    // conv neighbors: shuffles executed UNCONDITIONALLY by all 64 lanes
    // (convergent op — must not sit inside a per-lane ternary), then select halo.
    const float sm = __shfl(u0v, (lane + 63) & 63, 64);
    const float sp = __shfl(u0v, (lane + 1)  & 63, 64);
    const float um  = edge_lo ? hv : sm;
    const float upv = edge_hi ? hv : sp;

    const float dv = dcur + DB[c];
    const float d  = (dv > 15.f) ? dv : __logf(1.f + __expf(dv));   // softplus

    float xx = fmaf(Wk0[c], um, fmaf(Wk1[c], u0v, fmaf(Wk2[c], upv, CB[c])));
    const float u = xx * __builtin_amdgcn_rcpf(1.f + __expf(-xx));  // silu

    float s = 0.f;
#pragma unroll
    for (int n = 0; n < N_; ++n) s = fmaf(a[n], g[n], s);

    Ys[c * YSP + lane] = f2bf(d * d * u * s);
  }
  __syncthreads();

  // [l][c] store as packed uints (2 channels per store); incremental div (256 = 10*24+16)
  {
    uint* yTu = reinterpret_cast<uint*>(yT);
    int dl = tid / 24, j = tid - (tid / 24) * 24;
    for (int e = tid; e < 64 * 24; e += 256) {
      const uint lo = Ys[(2 * j    ) * YSP + dl];
      const uint hi = Ys[(2 * j + 1) * YSP + dl];
      yTu[((size_t)b * S_ + l0 + dl) * 384 + k * 24 + j] = lo | (hi << 16);
      dl += 10; j += 16; if (j >= 24) { j -= 24; dl += 1; }
    }
  }
}

// ---------------- GEMM2 (m97 structure): out = yT @ W2^T + out_b  (f32 out)
__global__ __launch_bounds__(256)
void gemm_mfma_bt(const ushort* __restrict__ A, const ushort* __restrict__ Bm,
                  const float* __restrict__ bias, float* __restrict__ Cc)
{
  __shared__ ushort As[128 * 32];
  __shared__ ushort Bs[128 * 32];

  const int lin = blockIdx.x;
  const int swz = (lin & 7) * 192 + (lin >> 3);
  const int bn  = (swz % 6) * 128;
  const int bm  = (swz / 6) * 128;

  const int tid  = threadIdx.x;
  const int wid  = tid >> 6, lane = tid & 63;
  const int wr   = wid >> 1, wc   = wid & 1;
  const int lr   = lane & 15, lg  = lane >> 4;
  const int srow = lane >> 2;
  const int scol = (lane & 3) * 8;

  f32x4 acc[4][4];
#pragma unroll
  for (int i = 0; i < 4; ++i)
#pragma unroll
    for (int j = 0; j < 4; ++j) acc[i][j] = (f32x4){0.f, 0.f, 0.f, 0.f};

  for (int k0 = 0; k0 < 768; k0 += 32) {
#pragma unroll
    for (int jj = 0; jj < 2; ++jj) {
      const int j = wid * 2 + jj;
      const ushort* ga = A  + (size_t)(bm + j * 16 + srow) * 768 + k0 + scol;
      __builtin_amdgcn_global_load_lds(
          (const __attribute__((address_space(1))) void*)ga,
          (__attribute__((address_space(3))) void*)(As + j * 512), 16, 0, 0);
      const ushort* gb = Bm + (size_t)(bn + j * 16 + srow) * 768 + k0 + scol;
      __builtin_amdgcn_global_load_lds(
          (const __attribute__((address_space(1))) void*)gb,
          (__attribute__((address_space(3))) void*)(Bs + j * 512), 16, 0, 0);
    }
    __syncthreads();

    bf16x8 af[4], bfr[4];
    const int ab = (wr * 64 + lr) * 32 + lg * 8;
    const int bb = (wc * 64 + lr) * 32 + lg * 8;
#pragma unroll
    for (int mf = 0; mf < 4; ++mf) af[mf]  = *reinterpret_cast<const bf16x8*>(&As[ab + mf * 512]);
#pragma unroll
    for (int nf = 0; nf < 4; ++nf) bfr[nf] = *reinterpret_cast<const bf16x8*>(&Bs[bb + nf * 512]);
#pragma unroll
    for (int mf = 0; mf < 4; ++mf)
#pragma unroll
      for (int nf = 0; nf < 4; ++nf)
        acc[mf][nf] = __builtin_amdgcn_mfma_f32_16x16x32_bf16(af[mf], bfr[nf], acc[mf][nf], 0, 0, 0);
    __syncthreads();
  }

#pragma unroll
  for (int nf = 0; nf < 4; ++nf) {
    const int n  = bn + wc * 64 + nf * 16 + lr;
    const float bv = bias[n];
#pragma unroll
    for (int mf = 0; mf < 4; ++mf) {
      const int m0 = bm + wr * 64 + mf * 16 + lg * 4;
#pragma unroll
      for (int r = 0; r < 4; ++r)
        Cc[(size_t)(m0 + r) * 768 + n] = acc[mf][nf][r] + bv;
    }
  }
}

extern "C" void kernel_launch(void* const* d_in, const int* in_sizes, int n_in,
                              void* d_out, int out_size, void* d_ws, size_t ws_size,
                              hipStream_t stream) {
  const float* x      = (const float*)d_in[0];
  const float* in_w   = (const float*)d_in[1];   // (1536,768) — only rows [0,768) used
  const float* in_b   = (const float*)d_in[2];
  const float* convw  = (const float*)d_in[3];
  const float* convb  = (const float*)d_in[4];
  const float* out_w  = (const float*)d_in[5];
  const float* out_b  = (const float*)d_in[6];
  const float* Alog   = (const float*)d_in[7];
  const float* delta  = (const float*)d_in[8];
  const float* Bt     = (const float*)d_in[9];
  const float* Ct     = (const float*)d_in[10];
  const float* dbias  = (const float*)d_in[11];
  float* out = (float*)d_out;

  ushort* u0T = (ushort*)d_ws;               // (B,768,S) bf16 — TRANSPOSED u0
  ushort* yTb = u0T + (size_t)M_ * D_;       // (B,S,768) bf16
  ushort* wb1 = yTb + (size_t)M_ * D_;
  ushort* wb2 = wb1 + (size_t)D_ * D_;

  cvt_w<<<1152, 256, 0, stream>>>(in_w, out_w, wb1, wb2);
  gemm1_xf32<<<1536, 256, 0, stream>>>(x, wb1, in_b, u0T);
  fuse_mid<<<dim3(S_ / 64, K_, B_), 256, 0, stream>>>(u0T, delta, Bt, Ct, Alog,
                                                      convw, convb, dbias, yTb);
  gemm_mfma_bt<<<1536, 256, 0, stream>>>(yTb, wb2, out_b, out);
}